// Round 1
// 977.581 us; speedup vs baseline: 1.0386x; 1.0386x over previous
//
#include <hip/hip_runtime.h>
#include <hip/hip_bf16.h>

#define H 65536
#define DIMC 384

typedef __bf16 bf16x8 __attribute__((ext_vector_type(8)));
typedef float f32x4 __attribute__((ext_vector_type(4)));

__device__ __forceinline__ unsigned short f2bf(float x) {
    return __builtin_bit_cast(unsigned short, __float2bfloat16(x));
}
__device__ __forceinline__ float bf2f(unsigned short u) {
    return __bfloat162float(__builtin_bit_cast(__hip_bfloat16, u));
}

// ---------------------------------------------------------------------------
// Weight convert: f32 -> bf16.
//   m=0: cc_w1 [384,882] -> [384,896] zero-padded
//   m=1: cc_w2 [384,384]
//   m=2: cc_w3 [384,384]
//   m=3: c1_w1 -> rows 0..383   of stacked cA [768,384]
//   m=4: c2_w1 -> rows 384..767 of stacked cA [768,384]
//   m=5: c1_w2 -> cols 0..383   of concat-K cB [384,768]
//   m=6: c2_w2 -> cols 384..767 of concat-K cB [384,768]
//   m=7: bias prep: biasf[0:768] = stack(c1_b1, c2_b1); biasf[768:1152] = c1_b2+c2_b2
// ---------------------------------------------------------------------------
__global__ __launch_bounds__(256) void wconv_k(
    const float* __restrict__ w1, const float* __restrict__ w2, const float* __restrict__ w3,
    const float* __restrict__ c11, const float* __restrict__ c21,
    const float* __restrict__ c12, const float* __restrict__ c22,
    const float* __restrict__ b11, const float* __restrict__ b21,
    const float* __restrict__ b12, const float* __restrict__ b22,
    unsigned short* __restrict__ dst, float* __restrict__ biasf)
{
    int m = blockIdx.y;
    int gid = blockIdx.x * 256 + threadIdx.x;
    if (m == 7) {
        if (gid < 384)       biasf[gid] = b11[gid];
        else if (gid < 768)  biasf[gid] = b21[gid - 384];
        else if (gid < 1152) biasf[gid] = b12[gid - 768] + b22[gid - 768];
        return;
    }
    if (m == 0) {
        if (gid < 344064) {
            int n = gid / 896, k = gid - n * 896;
            dst[gid] = f2bf(k < 882 ? w1[n * 882 + k] : 0.f);
        }
        return;
    }
    if (gid >= 147456) return;
    const float* src; size_t doff; int Kp = 384, koff = 0;
    switch (m) {
        case 1:  src = c12; doff = 933888; Kp = 768; break;            // placeholder (reordered below)
        default: src = nullptr; doff = 0; break;
    }
    // explicit mapping (avoid switch fallthrough confusion):
    if (m == 1)      { src = w2;  doff = 344064;          Kp = 384; koff = 0;   }
    else if (m == 2) { src = w3;  doff = 491520;          Kp = 384; koff = 0;   }
    else if (m == 3) { src = c11; doff = 638976;          Kp = 384; koff = 0;   }
    else if (m == 4) { src = c21; doff = 638976 + 147456; Kp = 384; koff = 0;   }
    else if (m == 5) { src = c12; doff = 933888;          Kp = 768; koff = 0;   }
    else             { src = c22; doff = 933888;          Kp = 768; koff = 384; }
    int n = gid / 384, k = gid - n * 384;
    dst[doff + (size_t)n * Kp + koff + k] = f2bf(src[gid]);
}

// ---------------------------------------------------------------------------
// corr [882, H] f32  ->  [H, 896] bf16 (transpose + convert, zero pad k>=882)
// ---------------------------------------------------------------------------
__global__ __launch_bounds__(256) void corr_tconv(const float* __restrict__ src,
                                                  unsigned short* __restrict__ dst)
{
    __shared__ float tile[64][65];
    int hb = blockIdx.x * 64;
    int kb = blockIdx.y * 64;
    int t = threadIdx.x;
    int col = t & 63, r4 = t >> 6;
    #pragma unroll
    for (int p = 0; p < 16; ++p) {
        int row = p * 4 + r4;          // k offset
        int k = kb + row;
        tile[row][col] = (k < 882) ? src[(size_t)k * H + hb + col] : 0.f;
    }
    __syncthreads();
    #pragma unroll
    for (int p = 0; p < 16; ++p) {
        int hrow = p * 4 + r4;         // h offset
        dst[(size_t)(hb + hrow) * 896 + kb + col] = f2bf(tile[col][hrow]);
    }
}

// ---------------------------------------------------------------------------
// GEMM: out[h, c] = sum_k Act[h,k] * W[c,k] + bias[c]
// Tiles: 128 h x 128 c x BK=64. 256 threads = 4 waves, each wave 64h x 64c.
// MODE 0: outb[h*ldo+c] = bf16(relu(v))
// MODE 1: v += net_T + inp_T (strided [c][h] f32 reads); outf = v; outb = bf16(v)
// MODE 3: v += aux0[h,c](f32 trunk x); outf[(c)*H+h] = v (transposed net_out
//         store); outb = bf16(relu(v))
// Weights = MFMA A operand (m=c), activations = B operand (n=h).
//   D: col(n=h)=lane&15, row(m=c)=quad*4+reg -> 4 accs are consecutive channels.
// ---------------------------------------------------------------------------
template<int MODE>
__global__ __launch_bounds__(256) void gemm_k(
    const unsigned short* __restrict__ W,    // [M, Kp] bf16
    const unsigned short* __restrict__ A,    // [H, Kp] bf16
    const float* __restrict__ bias,          // [M]
    const float* __restrict__ aux0,          // MODE1: net [384,H]; MODE3: xf [H,384]
    const float* __restrict__ aux1,          // MODE1: inp [384,H]
    unsigned short* __restrict__ outb,       // [H,ldo] bf16
    float* __restrict__ outf,                // MODE1: xf [H,384]; MODE3: net_out [384,H]
    int Kp, int ldo)
{
    __shared__ unsigned short Wt[128 * 64];
    __shared__ unsigned short At[128 * 64];
    const int tid  = threadIdx.x;
    const int lane = tid & 63;
    const int wave = tid >> 6;
    const int quad = lane >> 4;
    const int l15  = lane & 15;
    const int h0 = blockIdx.x * 128;
    const int c0 = blockIdx.y * 128;
    const int cw = (wave & 1) * 64;
    const int hw = (wave >> 1) * 64;

    const unsigned short* Wbase = W + (size_t)c0 * Kp;
    const unsigned short* Abase = A + (size_t)h0 * Kp;

    f32x4 acc[4][4];
    #pragma unroll
    for (int i = 0; i < 4; ++i)
        #pragma unroll
        for (int j = 0; j < 4; ++j)
            acc[i][j] = f32x4{0.f, 0.f, 0.f, 0.f};

    // Staging decomposition: tile row stride 64 bf16 = 128 B = 8 x 16B slots.
    // slot s = i*256 + tid  ->  row = i*32 + (tid>>3), k-elem = (tid&7)*8.
    const int srow = tid >> 3;
    const int skc  = (tid & 7) * 8;

    for (int kt = 0; kt < Kp; kt += 64) {
        __syncthreads();
        #pragma unroll
        for (int i = 0; i < 4; ++i) {
            const unsigned short* g = Wbase + (size_t)(i * 32 + srow) * Kp + kt + skc;
            char* lb = (char*)Wt + (i * 256 + wave * 64) * 16;
            __builtin_amdgcn_global_load_lds((__attribute__((address_space(1))) void*)(void*)g,
                                             (__attribute__((address_space(3))) void*)lb, 16, 0, 0);
        }
        #pragma unroll
        for (int i = 0; i < 4; ++i) {
            const unsigned short* g = Abase + (size_t)(i * 32 + srow) * Kp + kt + skc;
            char* lb = (char*)At + (i * 256 + wave * 64) * 16;
            __builtin_amdgcn_global_load_lds((__attribute__((address_space(1))) void*)(void*)g,
                                             (__attribute__((address_space(3))) void*)lb, 16, 0, 0);
        }
        __syncthreads();

        const uint4* Wv = (const uint4*)Wt;
        const uint4* Av = (const uint4*)At;
        #pragma unroll
        for (int ks = 0; ks < 2; ++ks) {
            uint4 aw[4], bx[4];
            #pragma unroll
            for (int ci = 0; ci < 4; ++ci) aw[ci] = Wv[(cw + ci * 16 + l15) * 8 + ks * 4 + quad];
            #pragma unroll
            for (int hi = 0; hi < 4; ++hi) bx[hi] = Av[(hw + hi * 16 + l15) * 8 + ks * 4 + quad];
            #pragma unroll
            for (int ci = 0; ci < 4; ++ci)
                #pragma unroll
                for (int hi = 0; hi < 4; ++hi)
                    acc[ci][hi] = __builtin_amdgcn_mfma_f32_16x16x32_bf16(
                        __builtin_bit_cast(bf16x8, aw[ci]),
                        __builtin_bit_cast(bf16x8, bx[hi]),
                        acc[ci][hi], 0, 0, 0);
        }
    }

    // Epilogue
    #pragma unroll
    for (int ci = 0; ci < 4; ++ci) {
        const int c = c0 + cw + ci * 16 + quad * 4;
        f32x4 b4 = *(const f32x4*)(bias + c);
        #pragma unroll
        for (int hi = 0; hi < 4; ++hi) {
            const int h = h0 + hw + hi * 16 + l15;
            const size_t base = (size_t)h * ldo + c;
            f32x4 v = acc[ci][hi] + b4;
            if constexpr (MODE == 1) {
                // fused transpose-read of net & inp ([384,H] layout)
                #pragma unroll
                for (int r = 0; r < 4; ++r)
                    v[r] += aux0[(size_t)(c + r) * H + h] + aux1[(size_t)(c + r) * H + h];
                *(f32x4*)(outf + base) = v;
            }
            if constexpr (MODE == 3) {
                v += *(const f32x4*)(aux0 + base);
                // fused transposed store: net_out[c][h]
                #pragma unroll
                for (int r = 0; r < 4; ++r)
                    outf[(size_t)(c + r) * H + h] = v[r];
            }
            f32x4 s = v;
            if constexpr (MODE == 0 || MODE == 3) {
                s[0] = fmaxf(s[0], 0.f); s[1] = fmaxf(s[1], 0.f);
                s[2] = fmaxf(s[2], 0.f); s[3] = fmaxf(s[3], 0.f);
            }
            ushort4 o;
            o.x = f2bf(s[0]); o.y = f2bf(s[1]); o.z = f2bf(s[2]); o.w = f2bf(s[3]);
            *(ushort4*)(outb + base) = o;
        }
    }
}

// ---------------------------------------------------------------------------
// Heads: wave per h. d = r@dW^T + dB ; w = sigmoid(r@wW^T + wB)
// ---------------------------------------------------------------------------
__global__ __launch_bounds__(256) void heads_k(
    const unsigned short* __restrict__ r,
    const float* __restrict__ dW, const float* __restrict__ dB,
    const float* __restrict__ wW, const float* __restrict__ wB,
    float* __restrict__ out)
{
    __shared__ float wl[1536];
    int tid = threadIdx.x;
    for (int i = tid; i < 1536; i += 256)
        wl[i] = (i < 768) ? dW[i] : wW[i - 768];
    __syncthreads();
    int wave = tid >> 6, lane = tid & 63;
    int h = blockIdx.x * 4 + wave;
    const unsigned short* rp = r + (size_t)h * 384 + lane * 6;
    int c = lane * 6;
    float s0 = 0.f, s1 = 0.f, s2 = 0.f, s3 = 0.f;
    #pragma unroll
    for (int i = 0; i < 6; ++i) {
        float rv = bf2f(rp[i]);
        s0 += rv * wl[c + i];
        s1 += rv * wl[384 + c + i];
        s2 += rv * wl[768 + c + i];
        s3 += rv * wl[1152 + c + i];
    }
    #pragma unroll
    for (int m = 32; m >= 1; m >>= 1) {
        s0 += __shfl_xor(s0, m, 64);
        s1 += __shfl_xor(s1, m, 64);
        s2 += __shfl_xor(s2, m, 64);
        s3 += __shfl_xor(s3, m, 64);
    }
    if (lane == 0) {
        float* od = out + (size_t)384 * H;
        float* ow = out + (size_t)386 * H;
        od[h]     = s0 + dB[0];
        od[H + h] = s1 + dB[1];
        ow[h]     = 1.f / (1.f + __expf(-(s2 + wB[0])));
        ow[H + h] = 1.f / (1.f + __expf(-(s3 + wB[1])));
    }
}

// ---------------------------------------------------------------------------
extern "C" void kernel_launch(void* const* d_in, const int* in_sizes, int n_in,
                              void* d_out, int out_size, void* d_ws, size_t ws_size,
                              hipStream_t stream)
{
    const float* net   = (const float*)d_in[0];
    const float* inp   = (const float*)d_in[1];
    const float* corr  = (const float*)d_in[2];
    // d_in[3..6] = ii, jj, kk, kw: dummy path multiplied by 0.0 -> unused
    const float* cc_w1 = (const float*)d_in[7];
    const float* cc_b1 = (const float*)d_in[8];
    const float* cc_w2 = (const float*)d_in[9];
    const float* cc_b2 = (const float*)d_in[10];
    const float* cc_w3 = (const float*)d_in[11];
    const float* cc_b3 = (const float*)d_in[12];
    const float* c1_w1 = (const float*)d_in[13];
    const float* c1_b1 = (const float*)d_in[14];
    const float* c1_w2 = (const float*)d_in[15];
    const float* c1_b2 = (const float*)d_in[16];
    const float* c2_w1 = (const float*)d_in[17];
    const float* c2_b1 = (const float*)d_in[18];
    const float* c2_w2 = (const float*)d_in[19];
    const float* c2_b2 = (const float*)d_in[20];
    const float* d_wp  = (const float*)d_in[21];
    const float* d_bp  = (const float*)d_in[22];
    const float* w_wp  = (const float*)d_in[23];
    const float* w_bp  = (const float*)d_in[24];
    float* out = (float*)d_out;

    char* ws = (char*)d_ws;
    size_t off = 0;
    auto carve = [&](size_t bytes) -> char* {
        char* p = ws + off;
        off += (bytes + 255) & ~(size_t)255;
        return p;
    };
    unsigned short* Wreg  = (unsigned short*)carve((size_t)1228800 * 2);   // bf16 weights
    unsigned short* corrb = (unsigned short*)carve((size_t)H * 896 * 2);   // corr^T bf16, later [H,768] branch act
    unsigned short* t1    = (unsigned short*)carve((size_t)H * 384 * 2);   // t1 / r
    unsigned short* t2    = (unsigned short*)carve((size_t)H * 384 * 2);   // t2
    float*          xf    = (float*)carve((size_t)H * 384 * 4);            // f32 trunk x
    unsigned short* xb    = (unsigned short*)carve((size_t)H * 384 * 2);   // bf16 trunk x
    float*          biasf = (float*)carve((size_t)1152 * 4);               // stacked/summed biases

    unsigned short* w1b = Wreg;                  // [384,896]
    unsigned short* w2b = Wreg + 344064;         // [384,384]
    unsigned short* w3b = Wreg + 491520;         // [384,384]
    unsigned short* cAb = Wreg + 638976;         // [768,384] = stack(c1_w1, c2_w1)
    unsigned short* cBb = Wreg + 933888;         // [384,768] = concat_K(c1_w2, c2_w2)

    wconv_k<<<dim3(1344, 8), 256, 0, stream>>>(cc_w1, cc_w2, cc_w3, c1_w1, c2_w1, c1_w2, c2_w2,
                                               c1_b1, c2_b1, c1_b2, c2_b2, Wreg, biasf);
    corr_tconv<<<dim3(1024, 14), 256, 0, stream>>>(corr, corrb);

    // cc chain
    gemm_k<0><<<dim3(512, 3), 256, 0, stream>>>(w1b, corrb, cc_b1, nullptr, nullptr, t1, nullptr, 896, 384);
    gemm_k<0><<<dim3(512, 3), 256, 0, stream>>>(w2b, t1, cc_b2, nullptr, nullptr, t2, nullptr, 384, 384);
    // trunk: x = net + inp + cc  (fused transpose-read of net/inp; f32 xf + bf16 xb)
    gemm_k<1><<<dim3(512, 3), 256, 0, stream>>>(w3b, t2, cc_b3, net, inp, xb, xf, 384, 384);
    // both branch stage-1s in one row-stacked GEMM: [H,768] = relu([c1_w1;c2_w1] @ x)
    gemm_k<0><<<dim3(512, 6), 256, 0, stream>>>(cAb, xb, biasf, nullptr, nullptr, corrb, nullptr, 384, 768);
    // both branch stage-2s + combine in one concat-K GEMM:
    //   x_out = x + [c1_w2|c2_w2] @ [t1;u1]  -> transposed store to out; r = relu bf16 -> t1
    gemm_k<3><<<dim3(512, 3), 256, 0, stream>>>(cBb, corrb, biasf + 768, xf, nullptr, t1, out, 768, 384);

    heads_k<<<H / 4, 256, 0, stream>>>(t1, d_wp, d_bp, w_wp, w_bp, out);
}

// Round 2
// 947.859 us; speedup vs baseline: 1.0711x; 1.0314x over previous
//
#include <hip/hip_runtime.h>
#include <hip/hip_bf16.h>

#define H 65536
#define DIMC 384

typedef __bf16 bf16x8 __attribute__((ext_vector_type(8)));
typedef float f32x4 __attribute__((ext_vector_type(4)));

__device__ __forceinline__ unsigned short f2bf(float x) {
    return __builtin_bit_cast(unsigned short, __float2bfloat16(x));
}
__device__ __forceinline__ float bf2f(unsigned short u) {
    return __bfloat162float(__builtin_bit_cast(__hip_bfloat16, u));
}

// ---------------------------------------------------------------------------
// Weight convert: f32 -> bf16.
//   m=0: cc_w1 [384,882] -> [384,896] zero-padded
//   m=1: cc_w2 [384,384]
//   m=2: cc_w3 [384,384]
//   m=3: c1_w1 -> rows 0..383   of stacked cA [768,384]
//   m=4: c2_w1 -> rows 384..767 of stacked cA [768,384]
//   m=5: c1_w2 -> cols 0..383   of concat-K cB [384,768]
//   m=6: c2_w2 -> cols 384..767 of concat-K cB [384,768]
//   m=7: bias prep: biasf[0:768] = stack(c1_b1, c2_b1); biasf[768:1152] = c1_b2+c2_b2
// ---------------------------------------------------------------------------
__global__ __launch_bounds__(256) void wconv_k(
    const float* __restrict__ w1, const float* __restrict__ w2, const float* __restrict__ w3,
    const float* __restrict__ c11, const float* __restrict__ c21,
    const float* __restrict__ c12, const float* __restrict__ c22,
    const float* __restrict__ b11, const float* __restrict__ b21,
    const float* __restrict__ b12, const float* __restrict__ b22,
    unsigned short* __restrict__ dst, float* __restrict__ biasf)
{
    int m = blockIdx.y;
    int gid = blockIdx.x * 256 + threadIdx.x;
    if (m == 7) {
        if (gid < 384)       biasf[gid] = b11[gid];
        else if (gid < 768)  biasf[gid] = b21[gid - 384];
        else if (gid < 1152) biasf[gid] = b12[gid - 768] + b22[gid - 768];
        return;
    }
    if (m == 0) {
        if (gid < 344064) {
            int n = gid / 896, k = gid - n * 896;
            dst[gid] = f2bf(k < 882 ? w1[n * 882 + k] : 0.f);
        }
        return;
    }
    if (gid >= 147456) return;
    const float* src; size_t doff; int Kp = 384, koff = 0;
    if (m == 1)      { src = w2;  doff = 344064;          Kp = 384; koff = 0;   }
    else if (m == 2) { src = w3;  doff = 491520;          Kp = 384; koff = 0;   }
    else if (m == 3) { src = c11; doff = 638976;          Kp = 384; koff = 0;   }
    else if (m == 4) { src = c21; doff = 638976 + 147456; Kp = 384; koff = 0;   }
    else if (m == 5) { src = c12; doff = 933888;          Kp = 768; koff = 0;   }
    else             { src = c22; doff = 933888;          Kp = 768; koff = 384; }
    int n = gid / 384, k = gid - n * 384;
    dst[doff + (size_t)n * Kp + koff + k] = f2bf(src[gid]);
}

// ---------------------------------------------------------------------------
// corr [882, H] f32  ->  [H, 896] bf16 (transpose + convert, zero pad k>=882)
// ---------------------------------------------------------------------------
__global__ __launch_bounds__(256) void corr_tconv(const float* __restrict__ src,
                                                  unsigned short* __restrict__ dst)
{
    __shared__ float tile[64][65];
    int hb = blockIdx.x * 64;
    int kb = blockIdx.y * 64;
    int t = threadIdx.x;
    int col = t & 63, r4 = t >> 6;
    #pragma unroll
    for (int p = 0; p < 16; ++p) {
        int row = p * 4 + r4;          // k offset
        int k = kb + row;
        tile[row][col] = (k < 882) ? src[(size_t)k * H + hb + col] : 0.f;
    }
    __syncthreads();
    #pragma unroll
    for (int p = 0; p < 16; ++p) {
        int hrow = p * 4 + r4;         // h offset
        dst[(size_t)(hb + hrow) * 896 + kb + col] = f2bf(tile[col][hrow]);
    }
}

// ---------------------------------------------------------------------------
// GEMM: out[h, c] = sum_k Act[h,k] * W[c,k] + bias[c]
// Tiles: 128 h x 128 c x BK=64. 256 threads = 4 waves, each wave 64h x 64c.
// MODE 0: outb[h*ldo+c] = bf16(relu(v))
// MODE 1: v += net_T + inp_T (LDS-transposed, coalesced dwordx4); outf = v;
//         outb = bf16(v)
// MODE 3: v += aux0[h,c](f32 trunk x); outf[(c)*H+h] = v via LDS-staged
//         transposed dump (coalesced dwordx4); outb = bf16(relu(v))
// Weights = MFMA A operand (m=c), activations = B operand (n=h).
//   D: col(n=h)=lane&15, row(m=c)=quad*4+reg -> 4 accs are consecutive channels.
// LDS K-tiles are column-slot XOR-swizzled (T2, both-sides): global source slot
// (tid&7)^(row&7) feeds linear gload_lds dest; reads XOR slot with l15&7.
// Kills the 16-way (2x-over-minimum) ds_read_b128 bank serialization.
// ---------------------------------------------------------------------------
template<int MODE>
__global__ __launch_bounds__(256) void gemm_k(
    const unsigned short* __restrict__ W,    // [M, Kp] bf16
    const unsigned short* __restrict__ A,    // [H, Kp] bf16
    const float* __restrict__ bias,          // [M]
    const float* __restrict__ aux0,          // MODE1: net [384,H]; MODE3: xf [H,384]
    const float* __restrict__ aux1,          // MODE1: inp [384,H]
    unsigned short* __restrict__ outb,       // [H,ldo] bf16
    float* __restrict__ outf,                // MODE1: xf [H,384]; MODE3: net_out [384,H]
    int Kp, int ldo)
{
    __shared__ __align__(16) char SMEM[32768];
    unsigned short* Wt = (unsigned short*)SMEM;            // [128*64] bf16
    unsigned short* At = (unsigned short*)(SMEM + 16384);  // [128*64] bf16
    const int tid  = threadIdx.x;
    const int lane = tid & 63;
    const int wave = tid >> 6;
    const int quad = lane >> 4;
    const int l15  = lane & 15;
    const int h0 = blockIdx.x * 128;
    const int c0 = blockIdx.y * 128;
    const int cw = (wave & 1) * 64;
    const int hw = (wave >> 1) * 64;

    const unsigned short* Wbase = W + (size_t)c0 * Kp;
    const unsigned short* Abase = A + (size_t)h0 * Kp;

    f32x4 acc[4][4];
    #pragma unroll
    for (int i = 0; i < 4; ++i)
        #pragma unroll
        for (int j = 0; j < 4; ++j)
            acc[i][j] = f32x4{0.f, 0.f, 0.f, 0.f};

    // Staging decomposition: tile row stride 64 bf16 = 128 B = 8 x 16B slots.
    // LDS slot (row, j) holds global column chunk j^(row&7) (source pre-swizzle;
    // the 8 lanes of a row still cover one contiguous 128B segment).
    const int srow = tid >> 3;
    const int skc  = ((tid & 7) ^ (srow & 7)) * 8;
    const int rswz = l15 & 7;   // read-side slot XOR (row&7 == l15&7 for all frags)

    for (int kt = 0; kt < Kp; kt += 64) {
        __syncthreads();
        #pragma unroll
        for (int i = 0; i < 4; ++i) {
            const unsigned short* g = Wbase + (size_t)(i * 32 + srow) * Kp + kt + skc;
            char* lb = (char*)Wt + (i * 256 + wave * 64) * 16;
            __builtin_amdgcn_global_load_lds((__attribute__((address_space(1))) void*)(void*)g,
                                             (__attribute__((address_space(3))) void*)lb, 16, 0, 0);
        }
        #pragma unroll
        for (int i = 0; i < 4; ++i) {
            const unsigned short* g = Abase + (size_t)(i * 32 + srow) * Kp + kt + skc;
            char* lb = (char*)At + (i * 256 + wave * 64) * 16;
            __builtin_amdgcn_global_load_lds((__attribute__((address_space(1))) void*)(void*)g,
                                             (__attribute__((address_space(3))) void*)lb, 16, 0, 0);
        }
        __syncthreads();

        const uint4* Wv = (const uint4*)Wt;
        const uint4* Av = (const uint4*)At;
        #pragma unroll
        for (int ks = 0; ks < 2; ++ks) {
            uint4 aw[4], bx[4];
            #pragma unroll
            for (int ci = 0; ci < 4; ++ci)
                aw[ci] = Wv[(cw + ci * 16 + l15) * 8 + ((ks * 4 + quad) ^ rswz)];
            #pragma unroll
            for (int hi = 0; hi < 4; ++hi)
                bx[hi] = Av[(hw + hi * 16 + l15) * 8 + ((ks * 4 + quad) ^ rswz)];
            #pragma unroll
            for (int ci = 0; ci < 4; ++ci)
                #pragma unroll
                for (int hi = 0; hi < 4; ++hi)
                    acc[ci][hi] = __builtin_amdgcn_mfma_f32_16x16x32_bf16(
                        __builtin_bit_cast(bf16x8, aw[ci]),
                        __builtin_bit_cast(bf16x8, bx[hi]),
                        acc[ci][hi], 0, 0, 0);
        }
    }

    // ---- Epilogue ----
    // Hoist bias add (keeps f32 association identical to prior version:
    // ((acc+bias) + fused-adds)).
    #pragma unroll
    for (int ci = 0; ci < 4; ++ci) {
        const int c = c0 + cw + ci * 16 + quad * 4;
        f32x4 b4 = *(const f32x4*)(bias + c);
        #pragma unroll
        for (int hi = 0; hi < 4; ++hi) acc[ci][hi] += b4;
    }

    if constexpr (MODE == 1) {
        // acc += (net^T + inp^T) via LDS transpose: stage [128c][64h] f32 tiles
        // (coalesced dwordx4 rows), two h-halves, reusing the K-loop LDS.
        float* F = (float*)SMEM;
        __syncthreads();
        #pragma unroll
        for (int hh = 0; hh < 2; ++hh) {
            #pragma unroll 2
            for (int p = 0; p < 8; ++p) {
                int s = p * 256 + tid;
                int row = s >> 4, c4 = s & 15;
                size_t gi = (size_t)(c0 + row) * H + h0 + hh * 64 + c4 * 4;
                f32x4 a = *(const f32x4*)(aux0 + gi);
                f32x4 b = *(const f32x4*)(aux1 + gi);
                *(f32x4*)(F + row * 64 + c4 * 4) = a + b;
            }
            __syncthreads();
            if (hw == hh * 64) {
                #pragma unroll
                for (int ci = 0; ci < 4; ++ci)
                    #pragma unroll
                    for (int hi = 0; hi < 4; ++hi)
                        #pragma unroll
                        for (int r = 0; r < 4; ++r)
                            acc[ci][hi][r] += F[(cw + ci * 16 + quad * 4 + r) * 64 + hi * 16 + l15];
            }
            __syncthreads();
        }
    }

    if constexpr (MODE == 3) {
        // acc += xf[h,c] (coalesced f32x4), then transposed dump of x to
        // outf[c*H+h] via LDS staging (coalesced dwordx4 rows).
        #pragma unroll
        for (int ci = 0; ci < 4; ++ci) {
            const int c = c0 + cw + ci * 16 + quad * 4;
            #pragma unroll
            for (int hi = 0; hi < 4; ++hi) {
                const int h = h0 + hw + hi * 16 + l15;
                acc[ci][hi] += *(const f32x4*)(aux0 + (size_t)h * ldo + c);
            }
        }
        float* G = (float*)SMEM;
        __syncthreads();
        #pragma unroll
        for (int hh = 0; hh < 2; ++hh) {
            if (hw == hh * 64) {
                #pragma unroll
                for (int ci = 0; ci < 4; ++ci)
                    #pragma unroll
                    for (int hi = 0; hi < 4; ++hi)
                        #pragma unroll
                        for (int r = 0; r < 4; ++r)
                            G[(cw + ci * 16 + quad * 4 + r) * 64 + hi * 16 + l15] = acc[ci][hi][r];
            }
            __syncthreads();
            #pragma unroll 2
            for (int p = 0; p < 8; ++p) {
                int s = p * 256 + tid;
                int row = s >> 4, c4 = s & 15;
                *(f32x4*)(outf + (size_t)(c0 + row) * H + h0 + hh * 64 + c4 * 4) =
                    *(const f32x4*)(G + row * 64 + c4 * 4);
            }
            __syncthreads();
        }
    }

    // Final stores
    #pragma unroll
    for (int ci = 0; ci < 4; ++ci) {
        const int c = c0 + cw + ci * 16 + quad * 4;
        #pragma unroll
        for (int hi = 0; hi < 4; ++hi) {
            const int h = h0 + hw + hi * 16 + l15;
            const size_t base = (size_t)h * ldo + c;
            f32x4 v = acc[ci][hi];
            if constexpr (MODE == 1) {
                *(f32x4*)(outf + base) = v;
            }
            f32x4 s = v;
            if constexpr (MODE == 0 || MODE == 3) {
                s[0] = fmaxf(s[0], 0.f); s[1] = fmaxf(s[1], 0.f);
                s[2] = fmaxf(s[2], 0.f); s[3] = fmaxf(s[3], 0.f);
            }
            ushort4 o;
            o.x = f2bf(s[0]); o.y = f2bf(s[1]); o.z = f2bf(s[2]); o.w = f2bf(s[3]);
            *(ushort4*)(outb + base) = o;
        }
    }
}

// ---------------------------------------------------------------------------
// Heads: wave per h. d = r@dW^T + dB ; w = sigmoid(r@wW^T + wB)
// ---------------------------------------------------------------------------
__global__ __launch_bounds__(256) void heads_k(
    const unsigned short* __restrict__ r,
    const float* __restrict__ dW, const float* __restrict__ dB,
    const float* __restrict__ wW, const float* __restrict__ wB,
    float* __restrict__ out)
{
    __shared__ float wl[1536];
    int tid = threadIdx.x;
    for (int i = tid; i < 1536; i += 256)
        wl[i] = (i < 768) ? dW[i] : wW[i - 768];
    __syncthreads();
    int wave = tid >> 6, lane = tid & 63;
    int h = blockIdx.x * 4 + wave;
    const unsigned short* rp = r + (size_t)h * 384 + lane * 6;
    int c = lane * 6;
    float s0 = 0.f, s1 = 0.f, s2 = 0.f, s3 = 0.f;
    #pragma unroll
    for (int i = 0; i < 6; ++i) {
        float rv = bf2f(rp[i]);
        s0 += rv * wl[c + i];
        s1 += rv * wl[384 + c + i];
        s2 += rv * wl[768 + c + i];
        s3 += rv * wl[1152 + c + i];
    }
    #pragma unroll
    for (int m = 32; m >= 1; m >>= 1) {
        s0 += __shfl_xor(s0, m, 64);
        s1 += __shfl_xor(s1, m, 64);
        s2 += __shfl_xor(s2, m, 64);
        s3 += __shfl_xor(s3, m, 64);
    }
    if (lane == 0) {
        float* od = out + (size_t)384 * H;
        float* ow = out + (size_t)386 * H;
        od[h]     = s0 + dB[0];
        od[H + h] = s1 + dB[1];
        ow[h]     = 1.f / (1.f + __expf(-(s2 + wB[0])));
        ow[H + h] = 1.f / (1.f + __expf(-(s3 + wB[1])));
    }
}

// ---------------------------------------------------------------------------
extern "C" void kernel_launch(void* const* d_in, const int* in_sizes, int n_in,
                              void* d_out, int out_size, void* d_ws, size_t ws_size,
                              hipStream_t stream)
{
    const float* net   = (const float*)d_in[0];
    const float* inp   = (const float*)d_in[1];
    const float* corr  = (const float*)d_in[2];
    // d_in[3..6] = ii, jj, kk, kw: dummy path multiplied by 0.0 -> unused
    const float* cc_w1 = (const float*)d_in[7];
    const float* cc_b1 = (const float*)d_in[8];
    const float* cc_w2 = (const float*)d_in[9];
    const float* cc_b2 = (const float*)d_in[10];
    const float* cc_w3 = (const float*)d_in[11];
    const float* cc_b3 = (const float*)d_in[12];
    const float* c1_w1 = (const float*)d_in[13];
    const float* c1_b1 = (const float*)d_in[14];
    const float* c1_w2 = (const float*)d_in[15];
    const float* c1_b2 = (const float*)d_in[16];
    const float* c2_w1 = (const float*)d_in[17];
    const float* c2_b1 = (const float*)d_in[18];
    const float* c2_w2 = (const float*)d_in[19];
    const float* c2_b2 = (const float*)d_in[20];
    const float* d_wp  = (const float*)d_in[21];
    const float* d_bp  = (const float*)d_in[22];
    const float* w_wp  = (const float*)d_in[23];
    const float* w_bp  = (const float*)d_in[24];
    float* out = (float*)d_out;

    char* ws = (char*)d_ws;
    size_t off = 0;
    auto carve = [&](size_t bytes) -> char* {
        char* p = ws + off;
        off += (bytes + 255) & ~(size_t)255;
        return p;
    };
    unsigned short* Wreg  = (unsigned short*)carve((size_t)1228800 * 2);   // bf16 weights
    unsigned short* corrb = (unsigned short*)carve((size_t)H * 896 * 2);   // corr^T bf16, later [H,768] branch act
    unsigned short* t1    = (unsigned short*)carve((size_t)H * 384 * 2);   // t1 / r
    unsigned short* t2    = (unsigned short*)carve((size_t)H * 384 * 2);   // t2
    float*          xf    = (float*)carve((size_t)H * 384 * 4);            // f32 trunk x
    unsigned short* xb    = (unsigned short*)carve((size_t)H * 384 * 2);   // bf16 trunk x
    float*          biasf = (float*)carve((size_t)1152 * 4);               // stacked/summed biases

    unsigned short* w1b = Wreg;                  // [384,896]
    unsigned short* w2b = Wreg + 344064;         // [384,384]
    unsigned short* w3b = Wreg + 491520;         // [384,384]
    unsigned short* cAb = Wreg + 638976;         // [768,384] = stack(c1_w1, c2_w1)
    unsigned short* cBb = Wreg + 933888;         // [384,768] = concat_K(c1_w2, c2_w2)

    wconv_k<<<dim3(1344, 8), 256, 0, stream>>>(cc_w1, cc_w2, cc_w3, c1_w1, c2_w1, c1_w2, c2_w2,
                                               c1_b1, c2_b1, c1_b2, c2_b2, Wreg, biasf);
    corr_tconv<<<dim3(1024, 14), 256, 0, stream>>>(corr, corrb);

    // cc chain
    gemm_k<0><<<dim3(512, 3), 256, 0, stream>>>(w1b, corrb, cc_b1, nullptr, nullptr, t1, nullptr, 896, 384);
    gemm_k<0><<<dim3(512, 3), 256, 0, stream>>>(w2b, t1, cc_b2, nullptr, nullptr, t2, nullptr, 384, 384);
    // trunk: x = net + inp + cc  (LDS-transposed read of net/inp; f32 xf + bf16 xb)
    gemm_k<1><<<dim3(512, 3), 256, 0, stream>>>(w3b, t2, cc_b3, net, inp, xb, xf, 384, 384);
    // both branch stage-1s in one row-stacked GEMM: [H,768] = relu([c1_w1;c2_w1] @ x)
    gemm_k<0><<<dim3(512, 6), 256, 0, stream>>>(cAb, xb, biasf, nullptr, nullptr, corrb, nullptr, 384, 768);
    // both branch stage-2s + combine in one concat-K GEMM:
    //   x_out = x + [c1_w2|c2_w2] @ [t1;u1]  -> transposed store to out; r = relu bf16 -> t1
    gemm_k<3><<<dim3(512, 3), 256, 0, stream>>>(cBb, corrb, biasf + 768, xf, nullptr, t1, out, 768, 384);

    heads_k<<<H / 4, 256, 0, stream>>>(t1, d_wp, d_bp, w_wp, w_bp, out);
}